// Round 3
// baseline (47773.035 us; speedup 1.0000x reference)
//
#include <hip/hip_runtime.h>
#include <hip/hip_cooperative_groups.h>
#include <math.h>

namespace cg = cooperative_groups;

#define Bn 128
#define Pn 625
#define ENCn 512
#define An 256
#define En 256
#define Hn 512
#define Vn 70
#define G4n 2048
#define STARTT 68
#define ENDT 69
#define NCHUNK 5
#define PCH 125
#define PSTRIDE 520
#define KSPLIT 16
#define KCH 80
#define GRID 640

struct Params {
  const float *enc, *emb, *We, *be, *Wd, *bd, *wf, *bf;
  const float *Wh0, *bh0, *Wc0, *bc0, *Wb, *bb;
  const float *Wih, *Whh, *bih, *bhh, *Wfc, *bfc;
  float *att1, *mean_enc;
  float *h0, *h1, *c0, *c1, *e0, *e1;
  float *att2, *gate, *part, *awe, *gatesP;
  float *rowval; int *rowidx; int *done;
  float *out; int T;
};

// ============ persistent cooperative kernel ============
__global__ __launch_bounds__(256, 3) void k_all(Params P) {
  cg::grid_group grid = cg::this_grid();
  const int blk = blockIdx.x, t = threadIdx.x;
  __shared__ float sm[4096];   // 16 KB, re-carved per phase
  __shared__ int tokS;

  // ---- setup phase 1: mean_enc ----
  if (blk < 512) {
    int b = blk >> 2, q = blk & 3;
    if (t < 128) {
      int ch = q * 128 + t;
      const float* e = P.enc + (size_t)b * Pn * ENCn + ch;
      float s = 0.f;
      for (int p = 0; p < Pn; ++p) s += e[(size_t)p * ENCn];
      P.mean_enc[b * ENCn + ch] = s * (1.0f / 625.0f);
    }
  }
  grid.sync();

  // ---- setup phase 2: h0/c0, emb0, done, att1 GEMM ----
  if (blk < 512) {
    int b = blk >> 2, sel = (blk >> 1) & 1, half = blk & 1;
    float* ms = sm;
    ms[t] = P.mean_enc[b * ENCn + t];
    ms[t + 256] = P.mean_enc[b * ENCn + t + 256];
    __syncthreads();
    const float* W = sel ? P.Wc0 : P.Wh0;
    const float* bias = sel ? P.bc0 : P.bh0;
    float* o = sel ? P.c0 : P.h0;
    int ch = half * 256 + t;
    float s = bias[ch];
    for (int k = 0; k < Hn; ++k) s += ms[k] * W[(size_t)k * Hn + ch];
    o[b * Hn + ch] = s;
    __syncthreads();
  }
  if (blk < Bn) P.e0[blk * En + t] = P.emb[STARTT * En + t];
  if (blk == 0 && t == 0) *P.done = 0;

  // att1 = enc @ We + be, 1250 tiles of 128x128
  {
    float (*sA)[128] = (float(*)[128])sm;
    float (*sB)[128] = (float(*)[128])(sm + 2048);
    for (int j = blk; j < 1250; j += GRID) {
      int n0 = (j & 1) * 128, m0 = (j >> 1) * 128;
      int tm = (t >> 4) * 8, tn = (t & 15) * 8;
      float acc[8][8];
#pragma unroll
      for (int i = 0; i < 8; ++i)
#pragma unroll
        for (int jj = 0; jj < 8; ++jj) acc[i][jj] = 0.f;
      for (int k0 = 0; k0 < 512; k0 += 16) {
        __syncthreads();
#pragma unroll
        for (int i = 0; i < 8; ++i) {
          int idx = t + i * 256;
          int mm = idx >> 4, kk = idx & 15;
          sA[kk][mm] = P.enc[(size_t)(m0 + mm) * 512 + k0 + kk];
          int kk2 = idx >> 7, nn = idx & 127;
          sB[kk2][nn] = P.We[(size_t)(k0 + kk2) * 256 + n0 + nn];
        }
        __syncthreads();
#pragma unroll
        for (int kk = 0; kk < 16; ++kk) {
          float a[8], bq[8];
          *(float4*)&a[0] = *(const float4*)&sA[kk][tm];
          *(float4*)&a[4] = *(const float4*)&sA[kk][tm + 4];
          *(float4*)&bq[0] = *(const float4*)&sB[kk][tn];
          *(float4*)&bq[4] = *(const float4*)&sB[kk][tn + 4];
#pragma unroll
          for (int i = 0; i < 8; ++i)
#pragma unroll
            for (int jj = 0; jj < 8; ++jj) acc[i][jj] += a[i] * bq[jj];
        }
      }
      float ber[8];
      *(float4*)&ber[0] = *(const float4*)&P.be[n0 + tn];
      *(float4*)&ber[4] = *(const float4*)&P.be[n0 + tn + 4];
#pragma unroll
      for (int i = 0; i < 8; ++i) {
        float o2[8];
#pragma unroll
        for (int jj = 0; jj < 8; ++jj) o2[jj] = acc[i][jj] + ber[jj];
        *(float4*)&P.att1[(size_t)(m0 + tm + i) * An + n0 + tn] = *(float4*)&o2[0];
        *(float4*)&P.att1[(size_t)(m0 + tm + i) * An + n0 + tn + 4] = *(float4*)&o2[4];
      }
      __syncthreads();
    }
  }
  grid.sync();

  // ================= main decode loop =================
  for (int st = 0; st < P.T; ++st) {
    const float* hc = (st & 1) ? P.h1 : P.h0;
    float* hn = (st & 1) ? P.h0 : P.h1;
    const float* cc = (st & 1) ? P.c1 : P.c0;
    float* cn = (st & 1) ? P.c0 : P.c1;
    const float* ec = (st & 1) ? P.e1 : P.e0;
    float* en = (st & 1) ? P.e0 : P.e1;

    // ---- phase P: proj (att2, gate) + flat-argmax done ----
    if (blk < 192) {
      int ct = blk % 12, rt = blk / 12;
      int n0 = ct * 64, r0 = rt * 8;
      float (*hsv)[Hn] = (float(*)[Hn])sm;
#pragma unroll
      for (int i = 0; i < 4; ++i) {
        int f4 = t + i * 256;
        int row = f4 >> 7, k4 = f4 & 127;
        *(float4*)&hsv[row][k4 * 4] = *(const float4*)&hc[(size_t)(r0 + row) * Hn + k4 * 4];
      }
      __syncthreads();
      int c = t & 63;
      int ra = (t >> 6) * 2;
      const float* Wp; int stride, lc;
      if (ct < 4) { lc = n0 + c; Wp = P.Wd + lc; stride = An; }
      else        { lc = n0 - 256 + c; Wp = P.Wb + lc; stride = ENCn; }
      float acc0 = 0.f, acc1 = 0.f;
#pragma unroll 4
      for (int k = 0; k < Hn; ++k) {
        float wv = Wp[(size_t)k * stride];
        acc0 += hsv[ra][k] * wv;
        acc1 += hsv[ra + 1][k] * wv;
      }
      if (ct < 4) {
        float bias = P.bd[lc];
        P.att2[(r0 + ra) * An + lc] = acc0 + bias;
        P.att2[(r0 + ra + 1) * An + lc] = acc1 + bias;
      } else {
        float bias = P.bb[lc];
        P.gate[(r0 + ra) * ENCn + lc] = 1.f / (1.f + expf(-(acc0 + bias)));
        P.gate[(r0 + ra + 1) * ENCn + lc] = 1.f / (1.f + expf(-(acc1 + bias)));
      }
    } else if (blk == 192 && st > 0) {
      float* sv = sm;
      int* si = (int*)(sm + 256);
      if (t < 128) { sv[t] = P.rowval[t]; si[t] = t * Vn + P.rowidx[t]; }
      __syncthreads();
      for (int s = 64; s > 0; s >>= 1) {
        if (t < s) {
          if (sv[t + s] > sv[t] || (sv[t + s] == sv[t] && si[t + s] < si[t])) {
            sv[t] = sv[t + s]; si[t] = si[t + s];
          }
        }
        __syncthreads();
      }
      if (t == 0 && si[0] == ENDT) *P.done = 1;
    }
    grid.sync();

    // ---- phase A: fused e -> chunk softmax -> partial awe ----
    {
      int c = blk % NCHUNK, b = blk / NCHUNK;
      int lane = t & 63, wv4 = t >> 6;
      int p0 = c * PCH;
      float* es = sm;
      float* red = sm + 128;
      float4 a2 = ((const float4*)(P.att2 + b * An))[lane];
      float4 wfr = ((const float4*)P.wf)[lane];
      float bfv = *P.bf;
      const float* a1b = P.att1 + ((size_t)b * Pn + p0) * An;
      for (int p = wv4; p < PCH; p += 4) {
        float4 v = ((const float4*)(a1b + (size_t)p * An))[lane];
        float s = fmaxf(v.x + a2.x, 0.f) * wfr.x
                + fmaxf(v.y + a2.y, 0.f) * wfr.y
                + fmaxf(v.z + a2.z, 0.f) * wfr.z
                + fmaxf(v.w + a2.w, 0.f) * wfr.w;
        for (int o = 32; o > 0; o >>= 1) s += __shfl_down(s, o, 64);
        if (lane == 0) es[p] = s + bfv;
      }
      __syncthreads();
      float m = -1e30f;
      for (int i = t; i < PCH; i += 256) m = fmaxf(m, es[i]);
      red[t] = m;
      __syncthreads();
      for (int s = 128; s > 0; s >>= 1) {
        if (t < s) red[t] = fmaxf(red[t], red[t + s]);
        __syncthreads();
      }
      m = red[0];
      __syncthreads();
      float lp = 0.f;
      for (int i = t; i < PCH; i += 256) {
        float e2 = expf(es[i] - m);
        es[i] = e2;
        lp += e2;
      }
      red[t] = lp;
      __syncthreads();
      for (int s = 128; s > 0; s >>= 1) {
        if (t < s) red[t] += red[t + s];
        __syncthreads();
      }
      float l = red[0];
      float acc0 = 0.f, acc1 = 0.f;
      const float2* eb2 = (const float2*)(P.enc + ((size_t)b * Pn + p0) * ENCn);
#pragma unroll 5
      for (int p = 0; p < PCH; ++p) {
        float wp = es[p];
        float2 v = eb2[(size_t)p * 256 + t];
        acc0 += wp * v.x;
        acc1 += wp * v.y;
      }
      float* pp = P.part + (size_t)(b * NCHUNK + c) * PSTRIDE;
      if (t == 0) { pp[0] = m; pp[1] = l; }
      ((float2*)(pp + 8))[t] = make_float2(acc0, acc1);
    }
    grid.sync();

    // ---- phase C: combine chunks + gate ----
    if (blk < Bn) {
      int b = blk;
      const float* pb = P.part + (size_t)b * NCHUNK * PSTRIDE;
      float M = -1e30f;
#pragma unroll
      for (int c = 0; c < NCHUNK; ++c) M = fmaxf(M, pb[c * PSTRIDE]);
      float L = 0.f, sc[NCHUNK];
#pragma unroll
      for (int c = 0; c < NCHUNK; ++c) {
        float s = expf(pb[c * PSTRIDE] - M);
        sc[c] = s;
        L += s * pb[c * PSTRIDE + 1];
      }
      float inv = 1.f / L;
      float a0 = 0.f, a1 = 0.f;
#pragma unroll
      for (int c = 0; c < NCHUNK; ++c) {
        float2 v = ((const float2*)(pb + c * PSTRIDE + 8))[t];
        a0 += sc[c] * v.x;
        a1 += sc[c] * v.y;
      }
      float2 g = ((const float2*)(P.gate + b * ENCn))[t];
      ((float2*)(P.awe + b * ENCn))[t] = make_float2(a0 * inv * g.x, a1 * inv * g.y);
    }
    grid.sync();

    // ---- phase G: gates split-K GEMM ----
    if (blk < 512) {
      int n0 = (blk & 31) * 64;
      int sI = blk >> 5;
      int k0 = sI * KCH;
      int tc = t & 15, tg = t >> 4;
      int nc = n0 + tc * 4;
      float4 acc[8];
#pragma unroll
      for (int r = 0; r < 8; ++r) acc[r] = make_float4(0.f, 0.f, 0.f, 0.f);
      for (int kk = 0; kk < KCH; kk += 4) {
        int k = k0 + kk;
        const float* wbase = (k < 768) ? (P.Wih + (size_t)k * G4n + nc)
                                       : (P.Whh + (size_t)(k - 768) * G4n + nc);
        float4 w0 = *(const float4*)(wbase);
        float4 w1 = *(const float4*)(wbase + G4n);
        float4 w2 = *(const float4*)(wbase + 2 * G4n);
        float4 w3 = *(const float4*)(wbase + 3 * G4n);
#pragma unroll
        for (int r = 0; r < 8; ++r) {
          int row = tg * 8 + r;
          float4 xv;
          if (k < 256)      xv = *(const float4*)(ec + row * En + k);
          else if (k < 768) xv = *(const float4*)(P.awe + row * ENCn + (k - 256));
          else              xv = *(const float4*)(hc + row * Hn + (k - 768));
          acc[r].x += xv.x * w0.x + xv.y * w1.x + xv.z * w2.x + xv.w * w3.x;
          acc[r].y += xv.x * w0.y + xv.y * w1.y + xv.z * w2.y + xv.w * w3.y;
          acc[r].z += xv.x * w0.z + xv.y * w1.z + xv.z * w2.z + xv.w * w3.z;
          acc[r].w += xv.x * w0.w + xv.y * w1.w + xv.z * w2.w + xv.w * w3.w;
        }
      }
#pragma unroll
      for (int r = 0; r < 8; ++r)
        *(float4*)(P.gatesP + ((size_t)sI * Bn + tg * 8 + r) * G4n + nc) = acc[r];
    }
    grid.sync();

    // ---- phase L: lstm pointwise + preds GEMV + argmax + emb feedback ----
    if (blk < Bn) {
      int b = blk;
      float* hs2 = sm;
      float* ps = sm + 512;
#pragma unroll
      for (int uu = 0; uu < 2; ++uu) {
        int u = t + uu * 256;
        float gi = P.bih[u] + P.bhh[u];
        float gf = P.bih[u + 512] + P.bhh[u + 512];
        float gg = P.bih[u + 1024] + P.bhh[u + 1024];
        float go = P.bih[u + 1536] + P.bhh[u + 1536];
        for (int s = 0; s < KSPLIT; ++s) {
          const float* row = P.gatesP + ((size_t)s * Bn + b) * G4n;
          gi += row[u];
          gf += row[u + 512];
          gg += row[u + 1024];
          go += row[u + 1536];
        }
        float cv = (1.f / (1.f + expf(-gf))) * cc[b * Hn + u]
                 + (1.f / (1.f + expf(-gi))) * tanhf(gg);
        float hv = (1.f / (1.f + expf(-go))) * tanhf(cv);
        cn[b * Hn + u] = cv;
        hn[b * Hn + u] = hv;
        hs2[u] = hv;
      }
      __syncthreads();
      int lane = t & 63, wvi = t >> 6;
      for (int v = wvi; v < Vn; v += 4) {
        float s = 0.f;
        for (int k = lane; k < Hn; k += 64) s += hs2[k] * P.Wfc[(size_t)k * Vn + v];
        for (int o = 32; o > 0; o >>= 1) s += __shfl_down(s, o, 64);
        if (lane == 0) ps[v] = s + P.bfc[v];
      }
      __syncthreads();
      int dn = *(volatile int*)P.done;
      if (t < Vn) P.out[((size_t)b * P.T + st) * Vn + t] = dn ? 0.f : ps[t];
      if (t == 0) {
        float bv = ps[0]; int bi = 0;
        for (int v = 1; v < Vn; ++v)
          if (ps[v] > bv) { bv = ps[v]; bi = v; }
        P.rowval[b] = bv; P.rowidx[b] = bi; tokS = bi;
      }
      __syncthreads();
      en[b * En + t] = P.emb[tokS * En + t];
    }
    grid.sync();
  }
}

// ============ fallback multi-kernel path (round-2, known-good) ============

__global__ __launch_bounds__(256) void k_mean(const float* __restrict__ enc,
                                              float* __restrict__ mean_enc) {
  int b = blockIdx.x, t = threadIdx.x;
  const float* e = enc + (size_t)b * Pn * ENCn;
  float s0 = 0.f, s1 = 0.f;
  for (int p = 0; p < Pn; ++p) {
    s0 += e[(size_t)p * ENCn + t];
    s1 += e[(size_t)p * ENCn + t + 256];
  }
  mean_enc[b * ENCn + t] = s0 * (1.0f / 625.0f);
  mean_enc[b * ENCn + t + 256] = s1 * (1.0f / 625.0f);
}

__global__ __launch_bounds__(512) void k_init(const float* __restrict__ mean_enc,
                       const float* __restrict__ Wh0, const float* __restrict__ bh0,
                       const float* __restrict__ Wc0, const float* __restrict__ bc0,
                       const float* __restrict__ emb,
                       float* __restrict__ h0, float* __restrict__ c0,
                       float* __restrict__ emb_t, int* __restrict__ done_arr) {
  int b = blockIdx.x, t = threadIdx.x;
  const float* W = blockIdx.y ? Wc0 : Wh0;
  const float* bias = blockIdx.y ? bc0 : bh0;
  float* out = blockIdx.y ? c0 : h0;
  __shared__ float ms[ENCn];
  ms[t] = mean_enc[b * ENCn + t];
  __syncthreads();
  float s = bias[t];
  for (int k = 0; k < ENCn; ++k) s += ms[k] * W[k * Hn + t];
  out[b * Hn + t] = s;
  if (blockIdx.y == 0 && t < En) emb_t[b * En + t] = emb[STARTT * En + t];
  if (blockIdx.y == 0 && b == 0 && t == 0) done_arr[0] = 0;
}

__global__ __launch_bounds__(256) void k_att1(const float* __restrict__ Am,
                       const float* __restrict__ We,
                       const float* __restrict__ be, float* __restrict__ att1) {
  __shared__ float sA[16][128];
  __shared__ float sB[16][128];
  int n0 = blockIdx.x * 128, m0 = blockIdx.y * 128;
  int t = threadIdx.x;
  int tm = (t >> 4) * 8, tn = (t & 15) * 8;
  float acc[8][8];
#pragma unroll
  for (int i = 0; i < 8; ++i)
#pragma unroll
    for (int j = 0; j < 8; ++j) acc[i][j] = 0.f;
  for (int k0 = 0; k0 < 512; k0 += 16) {
    __syncthreads();
#pragma unroll
    for (int i = 0; i < 8; ++i) {
      int idx = t + i * 256;
      int mm = idx >> 4, kk = idx & 15;
      sA[kk][mm] = Am[(size_t)(m0 + mm) * 512 + k0 + kk];
      int kk2 = idx >> 7, nn = idx & 127;
      sB[kk2][nn] = We[(size_t)(k0 + kk2) * 256 + n0 + nn];
    }
    __syncthreads();
#pragma unroll
    for (int kk = 0; kk < 16; ++kk) {
      float a[8], bq[8];
      *(float4*)&a[0] = *(const float4*)&sA[kk][tm];
      *(float4*)&a[4] = *(const float4*)&sA[kk][tm + 4];
      *(float4*)&bq[0] = *(const float4*)&sB[kk][tn];
      *(float4*)&bq[4] = *(const float4*)&sB[kk][tn + 4];
#pragma unroll
      for (int i = 0; i < 8; ++i)
#pragma unroll
        for (int j = 0; j < 8; ++j) acc[i][j] += a[i] * bq[j];
    }
  }
  float ber[8];
  *(float4*)&ber[0] = *(const float4*)&be[n0 + tn];
  *(float4*)&ber[4] = *(const float4*)&be[n0 + tn + 4];
#pragma unroll
  for (int i = 0; i < 8; ++i) {
    float o[8];
#pragma unroll
    for (int j = 0; j < 8; ++j) o[j] = acc[i][j] + ber[j];
    *(float4*)&att1[(size_t)(m0 + tm + i) * An + n0 + tn] = *(float4*)&o[0];
    *(float4*)&att1[(size_t)(m0 + tm + i) * An + n0 + tn + 4] = *(float4*)&o[4];
  }
}

__global__ __launch_bounds__(256) void k_proj(const float* __restrict__ h,
                       const float* __restrict__ Wd, const float* __restrict__ bd,
                       const float* __restrict__ Wb, const float* __restrict__ bbv,
                       float* __restrict__ att2, float* __restrict__ gate,
                       const float* __restrict__ rowval, const int* __restrict__ rowidx,
                       int* __restrict__ done_f, int do_flat) {
  int t = threadIdx.x;
  if (blockIdx.x == 192) {
    if (!do_flat) return;
    __shared__ float sv[128];
    __shared__ int si[128];
    if (t < 128) { sv[t] = rowval[t]; si[t] = t * Vn + rowidx[t]; }
    __syncthreads();
    for (int s = 64; s > 0; s >>= 1) {
      if (t < s) {
        if (sv[t + s] > sv[t] || (sv[t + s] == sv[t] && si[t + s] < si[t])) {
          sv[t] = sv[t + s]; si[t] = si[t + s];
        }
      }
      __syncthreads();
    }
    if (t == 0 && si[0] == ENDT) *done_f = 1;
    return;
  }
  int ct = blockIdx.x % 12;
  int rt = blockIdx.x / 12;
  int n0 = ct * 64, r0 = rt * 8;
  __shared__ float hs[8][Hn];
#pragma unroll
  for (int i = 0; i < 4; ++i) {
    int f4 = t + i * 256;
    int row = f4 >> 7, k4 = f4 & 127;
    *(float4*)&hs[row][k4 * 4] = *(const float4*)&h[(size_t)(r0 + row) * Hn + k4 * 4];
  }
  __syncthreads();
  int c = t & 63;
  int ra = (t >> 6) * 2;
  const float* Wp; int stride, lc;
  if (ct < 4) { lc = n0 + c; Wp = Wd + lc; stride = An; }
  else        { lc = n0 - 256 + c; Wp = Wb + lc; stride = ENCn; }
  float acc0 = 0.f, acc1 = 0.f;
#pragma unroll 4
  for (int k = 0; k < Hn; ++k) {
    float wv = Wp[(size_t)k * stride];
    acc0 += hs[ra][k] * wv;
    acc1 += hs[ra + 1][k] * wv;
  }
  if (ct < 4) {
    float bias = bd[lc];
    att2[(r0 + ra) * An + lc] = acc0 + bias;
    att2[(r0 + ra + 1) * An + lc] = acc1 + bias;
  } else {
    float bias = bbv[lc];
    gate[(r0 + ra) * ENCn + lc] = 1.f / (1.f + expf(-(acc0 + bias)));
    gate[(r0 + ra + 1) * ENCn + lc] = 1.f / (1.f + expf(-(acc1 + bias)));
  }
}

__global__ __launch_bounds__(256) void k_attn(const float* __restrict__ att1,
                       const float* __restrict__ att2,
                       const float* __restrict__ wf, const float* __restrict__ bfp,
                       const float* __restrict__ enc, float* __restrict__ part) {
  int c = blockIdx.x, b = blockIdx.y, t = threadIdx.x;
  int lane = t & 63, wv = t >> 6;
  int p0 = c * PCH;
  __shared__ float es[PCH];
  __shared__ float red[256];
  float4 a2 = ((const float4*)(att2 + b * An))[lane];
  float4 wfr = ((const float4*)wf)[lane];
  float bfv = *bfp;
  const float* a1b = att1 + ((size_t)b * Pn + p0) * An;
  for (int p = wv; p < PCH; p += 4) {
    float4 v = ((const float4*)(a1b + (size_t)p * An))[lane];
    float s = fmaxf(v.x + a2.x, 0.f) * wfr.x
            + fmaxf(v.y + a2.y, 0.f) * wfr.y
            + fmaxf(v.z + a2.z, 0.f) * wfr.z
            + fmaxf(v.w + a2.w, 0.f) * wfr.w;
    for (int o = 32; o > 0; o >>= 1) s += __shfl_down(s, o, 64);
    if (lane == 0) es[p] = s + bfv;
  }
  __syncthreads();
  float m = -1e30f;
  for (int i = t; i < PCH; i += 256) m = fmaxf(m, es[i]);
  red[t] = m;
  __syncthreads();
  for (int s = 128; s > 0; s >>= 1) {
    if (t < s) red[t] = fmaxf(red[t], red[t + s]);
    __syncthreads();
  }
  m = red[0];
  __syncthreads();
  float lp = 0.f;
  for (int i = t; i < PCH; i += 256) {
    float e2 = expf(es[i] - m);
    es[i] = e2;
    lp += e2;
  }
  red[t] = lp;
  __syncthreads();
  for (int s = 128; s > 0; s >>= 1) {
    if (t < s) red[t] += red[t + s];
    __syncthreads();
  }
  float l = red[0];
  float acc0 = 0.f, acc1 = 0.f;
  const float2* eb2 = (const float2*)(enc + ((size_t)b * Pn + p0) * ENCn);
#pragma unroll 5
  for (int p = 0; p < PCH; ++p) {
    float wp = es[p];
    float2 v = eb2[(size_t)p * 256 + t];
    acc0 += wp * v.x;
    acc1 += wp * v.y;
  }
  float* pp = part + (size_t)(b * NCHUNK + c) * PSTRIDE;
  if (t == 0) { pp[0] = m; pp[1] = l; }
  ((float2*)(pp + 8))[t] = make_float2(acc0, acc1);
}

__global__ __launch_bounds__(256) void k_combine(const float* __restrict__ part,
                       const float* __restrict__ gate, float* __restrict__ awe) {
  int b = blockIdx.x, t = threadIdx.x;
  const float* pb = part + (size_t)b * NCHUNK * PSTRIDE;
  float M = -1e30f;
#pragma unroll
  for (int c = 0; c < NCHUNK; ++c) M = fmaxf(M, pb[c * PSTRIDE]);
  float L = 0.f, sc[NCHUNK];
#pragma unroll
  for (int c = 0; c < NCHUNK; ++c) {
    float s = expf(pb[c * PSTRIDE] - M);
    sc[c] = s;
    L += s * pb[c * PSTRIDE + 1];
  }
  float inv = 1.f / L;
  float a0 = 0.f, a1 = 0.f;
#pragma unroll
  for (int c = 0; c < NCHUNK; ++c) {
    float2 v = ((const float2*)(pb + c * PSTRIDE + 8))[t];
    a0 += sc[c] * v.x;
    a1 += sc[c] * v.y;
  }
  float2 g = ((const float2*)(gate + b * ENCn))[t];
  ((float2*)(awe + b * ENCn))[t] = make_float2(a0 * inv * g.x, a1 * inv * g.y);
}

__global__ __launch_bounds__(256) void k_gates(const float* __restrict__ embt,
                       const float* __restrict__ awe, const float* __restrict__ h,
                       const float* __restrict__ Wih, const float* __restrict__ Whh,
                       float* __restrict__ gp) {
  int n0 = blockIdx.x * 64;
  int sI = blockIdx.y;
  int k0 = sI * KCH;
  int t = threadIdx.x;
  int tc = t & 15, tg = t >> 4;
  int nc = n0 + tc * 4;
  float4 acc[8];
#pragma unroll
  for (int r = 0; r < 8; ++r) acc[r] = make_float4(0.f, 0.f, 0.f, 0.f);
  for (int kk = 0; kk < KCH; kk += 4) {
    int k = k0 + kk;
    const float* wbase = (k < 768) ? (Wih + (size_t)k * G4n + nc)
                                   : (Whh + (size_t)(k - 768) * G4n + nc);
    float4 w0 = *(const float4*)(wbase);
    float4 w1 = *(const float4*)(wbase + G4n);
    float4 w2 = *(const float4*)(wbase + 2 * G4n);
    float4 w3 = *(const float4*)(wbase + 3 * G4n);
#pragma unroll
    for (int r = 0; r < 8; ++r) {
      int row = tg * 8 + r;
      float4 xv;
      if (k < 256)      xv = *(const float4*)(embt + row * En + k);
      else if (k < 768) xv = *(const float4*)(awe + row * ENCn + (k - 256));
      else              xv = *(const float4*)(h + row * Hn + (k - 768));
      acc[r].x += xv.x * w0.x + xv.y * w1.x + xv.z * w2.x + xv.w * w3.x;
      acc[r].y += xv.x * w0.y + xv.y * w1.y + xv.z * w2.y + xv.w * w3.y;
      acc[r].z += xv.x * w0.z + xv.y * w1.z + xv.z * w2.z + xv.w * w3.z;
      acc[r].w += xv.x * w0.w + xv.y * w1.w + xv.z * w2.w + xv.w * w3.w;
    }
  }
#pragma unroll
  for (int r = 0; r < 8; ++r)
    *(float4*)(gp + ((size_t)sI * Bn + tg * 8 + r) * G4n + nc) = acc[r];
}

__global__ __launch_bounds__(512) void k_lstm(const float* __restrict__ gp,
                       const float* __restrict__ bih, const float* __restrict__ bhh,
                       const float* __restrict__ c_in, float* __restrict__ c_out,
                       float* __restrict__ h_out,
                       const float* __restrict__ Wfc, const float* __restrict__ bfc,
                       const float* __restrict__ emb,
                       float* __restrict__ rowval, int* __restrict__ rowidx,
                       float* __restrict__ emb_next, float* __restrict__ out,
                       const int* __restrict__ done_t, int step, int T) {
  int b = blockIdx.x, t = threadIdx.x;
  float gi = bih[t] + bhh[t];
  float gf = bih[t + 512] + bhh[t + 512];
  float gg = bih[t + 1024] + bhh[t + 1024];
  float go = bih[t + 1536] + bhh[t + 1536];
  for (int s = 0; s < KSPLIT; ++s) {
    const float* row = gp + ((size_t)s * Bn + b) * G4n;
    gi += row[t];
    gf += row[t + 512];
    gg += row[t + 1024];
    go += row[t + 1536];
  }
  float cv = (1.f / (1.f + expf(-gf))) * c_in[b * Hn + t]
           + (1.f / (1.f + expf(-gi))) * tanhf(gg);
  float hv = (1.f / (1.f + expf(-go))) * tanhf(cv);
  c_out[b * Hn + t] = cv;
  h_out[b * Hn + t] = hv;
  __shared__ float hs[Hn];
  __shared__ float ps[Vn];
  __shared__ int tokS2;
  hs[t] = hv;
  __syncthreads();
  int lane = t & 63, wvi = t >> 6;
  for (int v = wvi; v < Vn; v += 8) {
    float s = 0.f;
    for (int k = lane; k < Hn; k += 64) s += hs[k] * Wfc[(size_t)k * Vn + v];
    for (int o = 32; o > 0; o >>= 1) s += __shfl_down(s, o, 64);
    if (lane == 0) ps[v] = s + bfc[v];
  }
  __syncthreads();
  int done = *done_t;
  if (t < Vn) out[((size_t)b * T + step) * Vn + t] = done ? 0.f : ps[t];
  if (t == 0) {
    float bv = ps[0]; int bi = 0;
    for (int v = 1; v < Vn; ++v)
      if (ps[v] > bv) { bv = ps[v]; bi = v; }
    rowval[b] = bv; rowidx[b] = bi; tokS2 = bi;
  }
  __syncthreads();
  if (t < En) emb_next[b * En + t] = emb[tokS2 * En + t];
}

// ---------------- host ----------------

extern "C" void kernel_launch(void* const* d_in, const int* in_sizes, int n_in,
                              void* d_out, int out_size, void* d_ws, size_t ws_size,
                              hipStream_t stream) {
  const float* enc = (const float*)d_in[0];
  const float* emb = (const float*)d_in[1];
  const float* We  = (const float*)d_in[2];
  const float* be  = (const float*)d_in[3];
  const float* Wd  = (const float*)d_in[4];
  const float* bd  = (const float*)d_in[5];
  const float* wf  = (const float*)d_in[6];
  const float* bf  = (const float*)d_in[7];
  const float* Wh0 = (const float*)d_in[8];
  const float* bh0 = (const float*)d_in[9];
  const float* Wc0 = (const float*)d_in[10];
  const float* bc0 = (const float*)d_in[11];
  const float* Wb  = (const float*)d_in[12];
  const float* bb  = (const float*)d_in[13];
  const float* Wih = (const float*)d_in[14];
  const float* Whh = (const float*)d_in[15];
  const float* bih = (const float*)d_in[16];
  const float* bhh = (const float*)d_in[17];
  const float* Wfc = (const float*)d_in[18];
  const float* bfc = (const float*)d_in[19];
  int T = out_size / (Bn * Vn);  // 70

  float* w = (float*)d_ws;
  size_t off = 0;
  float* att1 = w + off;     off += (size_t)Bn * Pn * An;
  float* mean_enc = w + off; off += Bn * ENCn;
  float* hb0 = w + off;      off += Bn * Hn;
  float* hb1 = w + off;      off += Bn * Hn;
  float* cb0 = w + off;      off += Bn * Hn;
  float* cb1 = w + off;      off += Bn * Hn;
  float* eb0 = w + off;      off += Bn * En;
  float* eb1 = w + off;      off += Bn * En;
  float* att2 = w + off;     off += Bn * An;
  float* gate = w + off;     off += Bn * ENCn;
  float* part = w + off;     off += (size_t)Bn * NCHUNK * PSTRIDE;
  float* awe = w + off;      off += Bn * ENCn;
  float* gatesP = w + off;   off += (size_t)KSPLIT * Bn * G4n;
  float* rowval = w + off;   off += 256;
  off = (off + 255) & ~(size_t)255;
  int* rowidx = (int*)(w + off); off += 256;
  int* done_arr = (int*)(w + off);

  Params P;
  P.enc = enc; P.emb = emb; P.We = We; P.be = be; P.Wd = Wd; P.bd = bd;
  P.wf = wf; P.bf = bf; P.Wh0 = Wh0; P.bh0 = bh0; P.Wc0 = Wc0; P.bc0 = bc0;
  P.Wb = Wb; P.bb = bb; P.Wih = Wih; P.Whh = Whh; P.bih = bih; P.bhh = bhh;
  P.Wfc = Wfc; P.bfc = bfc;
  P.att1 = att1; P.mean_enc = mean_enc;
  P.h0 = hb0; P.h1 = hb1; P.c0 = cb0; P.c1 = cb1; P.e0 = eb0; P.e1 = eb1;
  P.att2 = att2; P.gate = gate; P.part = part; P.awe = awe; P.gatesP = gatesP;
  P.rowval = rowval; P.rowidx = rowidx; P.done = done_arr;
  P.out = (float*)d_out; P.T = T;

  void* args[] = { &P };
  hipError_t err = hipLaunchCooperativeKernel((void*)k_all, dim3(GRID), dim3(256),
                                              args, 0, stream);
  if (err == hipSuccess) return;

  // ---- fallback: known-good multi-kernel path ----
  float* hbuf[2] = {hb0, hb1};
  float* cbuf[2] = {cb0, cb1};
  float* ebuf[2] = {eb0, eb1};

  k_mean<<<Bn, 256, 0, stream>>>(enc, mean_enc);
  k_init<<<dim3(Bn, 2), 512, 0, stream>>>(mean_enc, Wh0, bh0, Wc0, bc0, emb,
                                          hb0, cb0, eb0, done_arr);
  k_att1<<<dim3(2, 625), 256, 0, stream>>>(enc, We, be, att1);

  int cur = 0;
  for (int t = 0; t < T; ++t) {
    int nxt = cur ^ 1;
    k_proj<<<193, 256, 0, stream>>>(hbuf[cur], Wd, bd, Wb, bb, att2, gate,
                                    rowval, rowidx, done_arr, t > 0 ? 1 : 0);
    k_attn<<<dim3(NCHUNK, Bn), 256, 0, stream>>>(att1, att2, wf, bf, enc, part);
    k_combine<<<Bn, 256, 0, stream>>>(part, gate, awe);
    k_gates<<<dim3(32, KSPLIT), 256, 0, stream>>>(ebuf[cur], awe, hbuf[cur], Wih, Whh, gatesP);
    k_lstm<<<Bn, 512, 0, stream>>>(gatesP, bih, bhh, cbuf[cur], cbuf[nxt], hbuf[nxt],
                                   Wfc, bfc, emb, rowval, rowidx, ebuf[nxt], (float*)d_out,
                                   done_arr, t, T);
    cur = nxt;
  }
}

// Round 4
// 12311.519 us; speedup vs baseline: 3.8804x; 3.8804x over previous
//
#include <hip/hip_runtime.h>
#include <math.h>

#define Bn 128
#define Pn 625
#define ENCn 512
#define An 256
#define En 256
#define Hn 512
#define Vn 70
#define G4n 2048
#define STARTT 68
#define ENDT 69
#define NCHUNK 5
#define PCH 125
#define PSTRIDE 520
#define KSPLIT 16
#define KCH 80

// ---------------- setup kernels ----------------

__global__ __launch_bounds__(256) void k_mean(const float* __restrict__ enc,
                                              float* __restrict__ mean_enc) {
  int b = blockIdx.x, t = threadIdx.x;
  const float* e = enc + (size_t)b * Pn * ENCn;
  float s0 = 0.f, s1 = 0.f;
  for (int p = 0; p < Pn; ++p) {
    s0 += e[(size_t)p * ENCn + t];
    s1 += e[(size_t)p * ENCn + t + 256];
  }
  mean_enc[b * ENCn + t] = s0 * (1.0f / 625.0f);
  mean_enc[b * ENCn + t + 256] = s1 * (1.0f / 625.0f);
}

__global__ __launch_bounds__(512) void k_init(const float* __restrict__ mean_enc,
                       const float* __restrict__ Wh0, const float* __restrict__ bh0,
                       const float* __restrict__ Wc0, const float* __restrict__ bc0,
                       const float* __restrict__ emb,
                       float* __restrict__ h0, float* __restrict__ c0,
                       float* __restrict__ emb_t, int* __restrict__ done_arr) {
  int b = blockIdx.x, t = threadIdx.x;
  const float* W = blockIdx.y ? Wc0 : Wh0;
  const float* bias = blockIdx.y ? bc0 : bh0;
  float* out = blockIdx.y ? c0 : h0;
  __shared__ float ms[ENCn];
  ms[t] = mean_enc[b * ENCn + t];
  __syncthreads();
  float s = bias[t];
  for (int k = 0; k < ENCn; ++k) s += ms[k] * W[k * Hn + t];
  out[b * Hn + t] = s;
  if (blockIdx.y == 0 && t < En) emb_t[b * En + t] = emb[STARTT * En + t];
  if (blockIdx.y == 0 && b == 0 && t == 0) done_arr[0] = 0;
}

// att1 = enc @ We + be : [80000,512] @ [512,256], fp32 tiled 128x128, kt=16
__global__ __launch_bounds__(256) void k_att1(const float* __restrict__ Am,
                       const float* __restrict__ We,
                       const float* __restrict__ be, float* __restrict__ att1) {
  __shared__ float sA[16][128];
  __shared__ float sB[16][128];
  int n0 = blockIdx.x * 128, m0 = blockIdx.y * 128;
  int t = threadIdx.x;
  int tm = (t >> 4) * 8, tn = (t & 15) * 8;
  float acc[8][8];
#pragma unroll
  for (int i = 0; i < 8; ++i)
#pragma unroll
    for (int j = 0; j < 8; ++j) acc[i][j] = 0.f;
  for (int k0 = 0; k0 < 512; k0 += 16) {
    __syncthreads();
#pragma unroll
    for (int i = 0; i < 8; ++i) {
      int idx = t + i * 256;
      int mm = idx >> 4, kk = idx & 15;
      sA[kk][mm] = Am[(size_t)(m0 + mm) * 512 + k0 + kk];
      int kk2 = idx >> 7, nn = idx & 127;
      sB[kk2][nn] = We[(size_t)(k0 + kk2) * 256 + n0 + nn];
    }
    __syncthreads();
#pragma unroll
    for (int kk = 0; kk < 16; ++kk) {
      float a[8], bq[8];
      *(float4*)&a[0] = *(const float4*)&sA[kk][tm];
      *(float4*)&a[4] = *(const float4*)&sA[kk][tm + 4];
      *(float4*)&bq[0] = *(const float4*)&sB[kk][tn];
      *(float4*)&bq[4] = *(const float4*)&sB[kk][tn + 4];
#pragma unroll
      for (int i = 0; i < 8; ++i)
#pragma unroll
        for (int j = 0; j < 8; ++j) acc[i][j] += a[i] * bq[j];
    }
  }
  float ber[8];
  *(float4*)&ber[0] = *(const float4*)&be[n0 + tn];
  *(float4*)&ber[4] = *(const float4*)&be[n0 + tn + 4];
#pragma unroll
  for (int i = 0; i < 8; ++i) {
    float o[8];
#pragma unroll
    for (int j = 0; j < 8; ++j) o[j] = acc[i][j] + ber[j];
    *(float4*)&att1[(size_t)(m0 + tm + i) * An + n0 + tn] = *(float4*)&o[0];
    *(float4*)&att1[(size_t)(m0 + tm + i) * An + n0 + tn + 4] = *(float4*)&o[4];
  }
}

// one-time proj from h0 (step 0 att2/gate). 192 blocks, R2-style tiling.
__global__ __launch_bounds__(256) void k_proj0(const float* __restrict__ h,
                       const float* __restrict__ Wd, const float* __restrict__ bd,
                       const float* __restrict__ Wb, const float* __restrict__ bbv,
                       float* __restrict__ att2, float* __restrict__ gate) {
  int t = threadIdx.x;
  int ct = blockIdx.x % 12;
  int rt = blockIdx.x / 12;
  int n0 = ct * 64, r0 = rt * 8;
  __shared__ float hs[8][Hn];
#pragma unroll
  for (int i = 0; i < 4; ++i) {
    int f4 = t + i * 256;
    int row = f4 >> 7, k4 = f4 & 127;
    *(float4*)&hs[row][k4 * 4] = *(const float4*)&h[(size_t)(r0 + row) * Hn + k4 * 4];
  }
  __syncthreads();
  int c = t & 63;
  int ra = (t >> 6) * 2;
  const float* Wp; int stride, lc;
  if (ct < 4) { lc = n0 + c; Wp = Wd + lc; stride = An; }
  else        { lc = n0 - 256 + c; Wp = Wb + lc; stride = ENCn; }
  float acc0 = 0.f, acc1 = 0.f;
#pragma unroll 4
  for (int k = 0; k < Hn; ++k) {
    float wv = Wp[(size_t)k * stride];
    acc0 += hs[ra][k] * wv;
    acc1 += hs[ra + 1][k] * wv;
  }
  if (ct < 4) {
    float bias = bd[lc];
    att2[(r0 + ra) * An + lc] = acc0 + bias;
    att2[(r0 + ra + 1) * An + lc] = acc1 + bias;
  } else {
    float bias = bbv[lc];
    gate[(r0 + ra) * ENCn + lc] = 1.f / (1.f + expf(-(acc0 + bias)));
    gate[(r0 + ra + 1) * ENCn + lc] = 1.f / (1.f + expf(-(acc1 + bias)));
  }
}

// ---------------- per-step kernels (4 launches/step) ----------------

// fused e -> chunk softmax -> partial weighted enc sum. grid 641 blocks x 512 thr.
// block 640: flat argmax over prev step's row maxima -> done update.
__global__ __launch_bounds__(512) void k_attn(const float* __restrict__ att1,
                       const float* __restrict__ att2,
                       const float* __restrict__ wf, const float* __restrict__ bfp,
                       const float* __restrict__ enc, float* __restrict__ part,
                       const float* __restrict__ rowval, const int* __restrict__ rowidx,
                       int* __restrict__ done_f, int do_flat) {
  int t = threadIdx.x;
  if (blockIdx.x == 640) {
    if (!do_flat) return;
    __shared__ float sv[128];
    __shared__ int si[128];
    if (t < 128) { sv[t] = rowval[t]; si[t] = t * Vn + rowidx[t]; }
    __syncthreads();
    for (int s = 64; s > 0; s >>= 1) {
      if (t < s) {
        if (sv[t + s] > sv[t] || (sv[t + s] == sv[t] && si[t + s] < si[t])) {
          sv[t] = sv[t + s]; si[t] = si[t + s];
        }
      }
      __syncthreads();
    }
    if (t == 0 && si[0] == ENDT) *done_f = 1;
    return;
  }
  int c = blockIdx.x % NCHUNK, b = blockIdx.x / NCHUNK;
  int lane = t & 63, wv = t >> 6;
  int p0 = c * PCH;
  __shared__ float es[128];
  __shared__ float red[512];
  __shared__ float4 vred[4][128];
  float4 a2 = ((const float4*)(att2 + b * An))[lane];
  float4 wfr = ((const float4*)wf)[lane];
  float bfv = *bfp;
  const float* a1b = att1 + ((size_t)b * Pn + p0) * An;
  // score pass: 8 waves, wave per p
  for (int p = wv; p < PCH; p += 8) {
    float4 v = ((const float4*)(a1b + (size_t)p * An))[lane];
    float s = fmaxf(v.x + a2.x, 0.f) * wfr.x
            + fmaxf(v.y + a2.y, 0.f) * wfr.y
            + fmaxf(v.z + a2.z, 0.f) * wfr.z
            + fmaxf(v.w + a2.w, 0.f) * wfr.w;
    for (int o = 32; o > 0; o >>= 1) s += __shfl_down(s, o, 64);
    if (lane == 0) es[p] = s + bfv;
  }
  __syncthreads();
  // chunk max (identical order to reference chunking)
  float m = (t < PCH) ? es[t] : -1e30f;
  red[t] = m;
  __syncthreads();
  for (int s = 256; s > 0; s >>= 1) {
    if (t < s) red[t] = fmaxf(red[t], red[t + s]);
    __syncthreads();
  }
  m = red[0];
  __syncthreads();
  // exp + chunk denom
  float lp = 0.f;
  if (t < PCH) { float e2 = expf(es[t] - m); es[t] = e2; lp = e2; }
  red[t] = lp;
  __syncthreads();
  for (int s = 256; s > 0; s >>= 1) {
    if (t < s) red[t] += red[t + s];
    __syncthreads();
  }
  float l = red[0];
  __syncthreads();
  // value pass: 4-way p-split, float4 cols; deterministic combine
  int tq = t >> 7, cg = t & 127;
  const float4* eb4 = (const float4*)(enc + ((size_t)b * Pn + p0) * ENCn);
  float4 acc = make_float4(0.f, 0.f, 0.f, 0.f);
  for (int p = tq; p < PCH; p += 4) {
    float wp = es[p];
    float4 v = eb4[(size_t)p * 128 + cg];
    acc.x += wp * v.x; acc.y += wp * v.y; acc.z += wp * v.z; acc.w += wp * v.w;
  }
  vred[tq][cg] = acc;
  __syncthreads();
  float* pp = part + (size_t)(b * NCHUNK + c) * PSTRIDE;
  if (t < 128) {
    float4 r0 = vred[0][t], r1 = vred[1][t], r2 = vred[2][t], r3 = vred[3][t];
    float4 r;
    r.x = ((r0.x + r1.x) + r2.x) + r3.x;
    r.y = ((r0.y + r1.y) + r2.y) + r3.y;
    r.z = ((r0.z + r1.z) + r2.z) + r3.z;
    r.w = ((r0.w + r1.w) + r2.w) + r3.w;
    ((float4*)(pp + 8))[t] = r;
  }
  if (t == 0) { pp[0] = m; pp[1] = l; }
}

__global__ __launch_bounds__(256) void k_combine(const float* __restrict__ part,
                       const float* __restrict__ gate, float* __restrict__ awe) {
  int b = blockIdx.x, t = threadIdx.x;
  const float* pb = part + (size_t)b * NCHUNK * PSTRIDE;
  float M = -1e30f;
#pragma unroll
  for (int c = 0; c < NCHUNK; ++c) M = fmaxf(M, pb[c * PSTRIDE]);
  float L = 0.f, sc[NCHUNK];
#pragma unroll
  for (int c = 0; c < NCHUNK; ++c) {
    float s = expf(pb[c * PSTRIDE] - M);
    sc[c] = s;
    L += s * pb[c * PSTRIDE + 1];
  }
  float inv = 1.f / L;
  float a0 = 0.f, a1 = 0.f;
#pragma unroll
  for (int c = 0; c < NCHUNK; ++c) {
    float2 v = ((const float2*)(pb + c * PSTRIDE + 8))[t];
    a0 += sc[c] * v.x;
    a1 += sc[c] * v.y;
  }
  float2 g = ((const float2*)(gate + b * ENCn))[t];
  ((float2*)(awe + b * ENCn))[t] = make_float2(a0 * inv * g.x, a1 * inv * g.y);
}

// gates split-K GEMM: X=[emb_t(256); awe(512); h(512)] @ [Wih;Whh] -> [128,2048] partials
__global__ __launch_bounds__(256) void k_gates(const float* __restrict__ embt,
                       const float* __restrict__ awe, const float* __restrict__ h,
                       const float* __restrict__ Wih, const float* __restrict__ Whh,
                       float* __restrict__ gp) {
  int n0 = blockIdx.x * 64;
  int sI = blockIdx.y;
  int k0 = sI * KCH;
  int t = threadIdx.x;
  int tc = t & 15, tg = t >> 4;
  int nc = n0 + tc * 4;
  float4 acc[8];
#pragma unroll
  for (int r = 0; r < 8; ++r) acc[r] = make_float4(0.f, 0.f, 0.f, 0.f);
  for (int kk = 0; kk < KCH; kk += 4) {
    int k = k0 + kk;
    const float* wbase = (k < 768) ? (Wih + (size_t)k * G4n + nc)
                                   : (Whh + (size_t)(k - 768) * G4n + nc);
    float4 w0 = *(const float4*)(wbase);
    float4 w1 = *(const float4*)(wbase + G4n);
    float4 w2 = *(const float4*)(wbase + 2 * G4n);
    float4 w3 = *(const float4*)(wbase + 3 * G4n);
#pragma unroll
    for (int r = 0; r < 8; ++r) {
      int row = tg * 8 + r;
      float4 xv;
      if (k < 256)      xv = *(const float4*)(embt + row * En + k);
      else if (k < 768) xv = *(const float4*)(awe + row * ENCn + (k - 256));
      else              xv = *(const float4*)(h + row * Hn + (k - 768));
      acc[r].x += xv.x * w0.x + xv.y * w1.x + xv.z * w2.x + xv.w * w3.x;
      acc[r].y += xv.x * w0.y + xv.y * w1.y + xv.z * w2.y + xv.w * w3.y;
      acc[r].z += xv.x * w0.z + xv.y * w1.z + xv.z * w2.z + xv.w * w3.z;
      acc[r].w += xv.x * w0.w + xv.y * w1.w + xv.z * w2.w + xv.w * w3.w;
    }
  }
#pragma unroll
  for (int r = 0; r < 8; ++r)
    *(float4*)(gp + ((size_t)sI * Bn + tg * 8 + r) * G4n + nc) = acc[r];
}

// split-K reduce + LSTM pointwise + preds GEMV + out write + argmax + emb feedback
// + FUSED proj for next step (att2, gate from h_new in LDS). grid(B) x 512.
__global__ __launch_bounds__(512) void k_lstm(const float* __restrict__ gp,
                       const float* __restrict__ bih, const float* __restrict__ bhh,
                       const float* __restrict__ c_in, float* __restrict__ c_out,
                       float* __restrict__ h_out,
                       const float* __restrict__ Wfc, const float* __restrict__ bfc,
                       const float* __restrict__ emb,
                       float* __restrict__ rowval, int* __restrict__ rowidx,
                       float* __restrict__ emb_next, float* __restrict__ out,
                       const int* __restrict__ done_t, int step, int T,
                       const float* __restrict__ Wd, const float* __restrict__ bd,
                       const float* __restrict__ Wb, const float* __restrict__ bbv,
                       float* __restrict__ att2, float* __restrict__ gate,
                       int do_proj) {
  int b = blockIdx.x, t = threadIdx.x;
  float gi = bih[t] + bhh[t];
  float gf = bih[t + 512] + bhh[t + 512];
  float gg = bih[t + 1024] + bhh[t + 1024];
  float go = bih[t + 1536] + bhh[t + 1536];
  for (int s = 0; s < KSPLIT; ++s) {
    const float* row = gp + ((size_t)s * Bn + b) * G4n;
    gi += row[t];
    gf += row[t + 512];
    gg += row[t + 1024];
    go += row[t + 1536];
  }
  float cv = (1.f / (1.f + expf(-gf))) * c_in[b * Hn + t]
           + (1.f / (1.f + expf(-gi))) * tanhf(gg);
  float hv = (1.f / (1.f + expf(-go))) * tanhf(cv);
  c_out[b * Hn + t] = cv;
  h_out[b * Hn + t] = hv;
  __shared__ float hs[Hn];
  __shared__ float ps[Vn];
  __shared__ int tokS;
  hs[t] = hv;
  __syncthreads();
  int lane = t & 63, wvi = t >> 6;
  for (int v = wvi; v < Vn; v += 8) {
    float s = 0.f;
    for (int k = lane; k < Hn; k += 64) s += hs[k] * Wfc[(size_t)k * Vn + v];
    for (int o = 32; o > 0; o >>= 1) s += __shfl_down(s, o, 64);
    if (lane == 0) ps[v] = s + bfc[v];
  }
  __syncthreads();
  int done = *done_t;
  if (t < Vn) out[((size_t)b * T + step) * Vn + t] = done ? 0.f : ps[t];
  if (t == 0) {
    float bv = ps[0]; int bi = 0;
    for (int v = 1; v < Vn; ++v)
      if (ps[v] > bv) { bv = ps[v]; bi = v; }
    rowval[b] = bv; rowidx[b] = bi; tokS = bi;
  }
  __syncthreads();
  if (t < En) emb_next[b * En + t] = emb[tokS * En + t];
  // fused proj for next step
  if (do_proj) {
    float s1 = bbv[t];
#pragma unroll 4
    for (int k = 0; k < Hn; ++k) s1 += hs[k] * Wb[(size_t)k * ENCn + t];
    gate[b * ENCn + t] = 1.f / (1.f + expf(-s1));
    if (t < An) {
      float s0 = bd[t];
#pragma unroll 4
      for (int k = 0; k < Hn; ++k) s0 += hs[k] * Wd[(size_t)k * An + t];
      att2[b * An + t] = s0;
    }
  }
}

// ---------------- host ----------------

extern "C" void kernel_launch(void* const* d_in, const int* in_sizes, int n_in,
                              void* d_out, int out_size, void* d_ws, size_t ws_size,
                              hipStream_t stream) {
  const float* enc = (const float*)d_in[0];
  const float* emb = (const float*)d_in[1];
  const float* We  = (const float*)d_in[2];
  const float* be  = (const float*)d_in[3];
  const float* Wd  = (const float*)d_in[4];
  const float* bd  = (const float*)d_in[5];
  const float* wf  = (const float*)d_in[6];
  const float* bf  = (const float*)d_in[7];
  const float* Wh0 = (const float*)d_in[8];
  const float* bh0 = (const float*)d_in[9];
  const float* Wc0 = (const float*)d_in[10];
  const float* bc0 = (const float*)d_in[11];
  const float* Wb  = (const float*)d_in[12];
  const float* bb  = (const float*)d_in[13];
  const float* Wih = (const float*)d_in[14];
  const float* Whh = (const float*)d_in[15];
  const float* bih = (const float*)d_in[16];
  const float* bhh = (const float*)d_in[17];
  const float* Wfc = (const float*)d_in[18];
  const float* bfc = (const float*)d_in[19];
  int T = out_size / (Bn * Vn);  // 70

  float* w = (float*)d_ws;
  size_t off = 0;
  float* att1 = w + off;     off += (size_t)Bn * Pn * An;
  float* mean_enc = w + off; off += Bn * ENCn;
  float* hb0 = w + off;      off += Bn * Hn;
  float* hb1 = w + off;      off += Bn * Hn;
  float* cb0 = w + off;      off += Bn * Hn;
  float* cb1 = w + off;      off += Bn * Hn;
  float* eb0 = w + off;      off += Bn * En;
  float* eb1 = w + off;      off += Bn * En;
  float* att2 = w + off;     off += Bn * An;
  float* gate = w + off;     off += Bn * ENCn;
  float* part = w + off;     off += (size_t)Bn * NCHUNK * PSTRIDE;
  float* awe = w + off;      off += Bn * ENCn;
  float* gatesP = w + off;   off += (size_t)KSPLIT * Bn * G4n;
  float* rowval = w + off;   off += 256;
  off = (off + 255) & ~(size_t)255;
  int* rowidx = (int*)(w + off); off += 256;
  int* done_arr = (int*)(w + off);

  float* hbuf[2] = {hb0, hb1};
  float* cbuf[2] = {cb0, cb1};
  float* ebuf[2] = {eb0, eb1};

  k_mean<<<Bn, 256, 0, stream>>>(enc, mean_enc);
  k_init<<<dim3(Bn, 2), 512, 0, stream>>>(mean_enc, Wh0, bh0, Wc0, bc0, emb,
                                          hb0, cb0, eb0, done_arr);
  k_att1<<<dim3(2, 625), 256, 0, stream>>>(enc, We, be, att1);
  k_proj0<<<192, 256, 0, stream>>>(hb0, Wd, bd, Wb, bb, att2, gate);

  int cur = 0;
  for (int t = 0; t < T; ++t) {
    int nxt = cur ^ 1;
    k_attn<<<641, 512, 0, stream>>>(att1, att2, wf, bf, enc, part,
                                    rowval, rowidx, done_arr, t > 0 ? 1 : 0);
    k_combine<<<Bn, 256, 0, stream>>>(part, gate, awe);
    k_gates<<<dim3(32, KSPLIT), 256, 0, stream>>>(ebuf[cur], awe, hbuf[cur], Wih, Whh, gatesP);
    k_lstm<<<Bn, 512, 0, stream>>>(gatesP, bih, bhh, cbuf[cur], cbuf[nxt], hbuf[nxt],
                                   Wfc, bfc, emb, rowval, rowidx, ebuf[nxt], (float*)d_out,
                                   done_arr, t, T,
                                   Wd, bd, Wb, bb, att2, gate, t < T - 1 ? 1 : 0);
    cur = nxt;
  }
}